// Round 1
// 139.623 us; speedup vs baseline: 1.0251x; 1.0251x over previous
//
#include <hip/hip_runtime.h>

// Problem constants (fixed by reference setup_inputs)
#define N_PRE 8192
#define N_CUR 16384
#define KNN   8

// Workspace layout (bytes):
//   [0,    64K) : c2p  u32[N_CUR]     nearest-pre index per cur point
//   [64K, 192K) : pre4 float4[N_PRE]  (-2px, -2py, -2pz, |p|^2)
//   [192K,448K) : cur4 float4[N_CUR]  ( cx,   cy,   cz,  |c|^2)
//
// Comparator trick: for a fixed query q, ordering by true sqdist equals
// ordering by (|cand|^2 - 2 cand.q)  -> 3 FMA per candidate.
//   A (query=cur, cand=pre): d = pre4.w + pre4.x*cx + pre4.y*cy + pre4.z*cz
//   B (query=pre, cand=cur): d = cur4.w + pre4.x*cx + pre4.y*cy + pre4.z*cz
// d can be NEGATIVE -> use monotone float->u32 key map on (rare) inserts.
//
// R1 change vs baseline: both big kernels previously launched 256 blocks
// (= 4096 waves = 50% of the chip's 8192-wave capacity; measured
// OccupancyPercent ~40, VALUBusy ~45 -> latency-bound). Halve per-wave
// work (A: 4->2 cur/wave, B: 2->1 pre/wave) so the grid doubles to 512
// blocks -> 32 waves/CU (100% theoretical occupancy) to hide the
// ds_read + shfl latency chains. Inner unroll 4->8 for more outstanding
// LDS reads per wave.

#define MAPPED_INF 0xFF800000u  // monotone key of +inf (empty-slot sentinel)

__device__ __forceinline__ unsigned key_of(float d) {
    unsigned b = __float_as_uint(d);
    return b ^ (0x80000000u | (unsigned)((int)b >> 31));
}
__device__ __forceinline__ float float_of_key(unsigned k) {
    unsigned b = (k & 0x80000000u) ? (k ^ 0x80000000u) : ~k;
    return __uint_as_float(b);
}
__device__ __forceinline__ unsigned shfl_u32(unsigned x, int src) {
    return (unsigned)__shfl((int)x, src);
}
__device__ __forceinline__ unsigned shfl_up1_u32(unsigned x) {
    return (unsigned)__shfl_up((int)x, 1);
}

// ---------- prep: pack comparator-form coords ----------
__global__ __launch_bounds__(256) void prep_kernel(
        const float* __restrict__ pre, const float* __restrict__ cur,
        float4* __restrict__ pre4, float4* __restrict__ cur4) {
    int i = blockIdx.x * 256 + threadIdx.x;
    if (i < N_CUR) {
        float x = cur[i], y = cur[N_CUR + i], z = cur[2 * N_CUR + i];
        cur4[i] = make_float4(x, y, z, fmaf(x, x, fmaf(y, y, z * z)));
    }
    if (i < N_PRE) {
        float x = pre[i], y = pre[N_PRE + i], z = pre[2 * N_PRE + i];
        pre4[i] = make_float4(-2.f * x, -2.f * y, -2.f * z,
                              fmaf(x, x, fmaf(y, y, z * z)));
    }
}

// ---------- Kernel A: cur2pre argmin ----------
// Wave owns 2 cur points; lanes scan pre candidates from an LDS tile.
// Per-lane branchless running min (strict < keeps lowest idx within the
// lane's ascending-index stream); cross-lane merge via packed-u64 min.
#define TILE_A 2048

__global__ __launch_bounds__(1024) void cur2pre_kernel(
        const float4* __restrict__ pre4, const float4* __restrict__ cur4,
        unsigned* __restrict__ c2p) {
    __shared__ float4 sp[TILE_A];
    const int tid  = threadIdx.x;
    const int lane = tid & 63;
    const int w    = tid >> 6;
    const int j0   = blockIdx.x * 32 + w * 2;   // this wave's 2 cur points

    const float4 c0 = cur4[j0 + 0];
    const float4 c1 = cur4[j0 + 1];

    const float INF = __int_as_float(0x7F800000);
    float b0 = INF, b1 = INF;
    int   i0 = 0,   i1 = 0;

    for (int tile = 0; tile < N_PRE; tile += TILE_A) {
        __syncthreads();
        for (int k = tid; k < TILE_A; k += 1024) sp[k] = pre4[tile + k];
        __syncthreads();

#pragma unroll 8
        for (int s = 0; s < TILE_A; s += 64) {
            float4 q = sp[s + lane];
            int idx = tile + s + lane;
            float d0 = fmaf(q.x, c0.x, fmaf(q.y, c0.y, fmaf(q.z, c0.z, q.w)));
            float d1 = fmaf(q.x, c1.x, fmaf(q.y, c1.y, fmaf(q.z, c1.z, q.w)));
            if (d0 < b0) { b0 = d0; i0 = idx; }
            if (d1 < b1) { b1 = d1; i1 = idx; }
        }
    }

    // cross-lane min with lowest-index tie-break via packed (key<<32 | idx)
    float        bs[2] = {b0, b1};
    int          is[2] = {i0, i1};
#pragma unroll
    for (int t = 0; t < 2; ++t) {
        unsigned long long v =
            (((unsigned long long)key_of(bs[t])) << 32) | (unsigned)is[t];
#pragma unroll
        for (int off = 32; off > 0; off >>= 1) {
            unsigned long long o = __shfl_xor((unsigned long long)v, off);
            v = (o < v) ? o : v;
        }
        if (lane == 0) c2p[j0 + t] = (unsigned)(v & 0xFFFFFFFFull);
    }
}

// ---------- Kernel B: per-pre top-8 + masked mean ----------
// Wave handles 1 pre point; 16 waves/block share one LDS cur tile.
// Fast path per candidate: 3 FMA + 1 float cmp (the ballot).
// Top-8 on lanes 0..7 as (monotone u32 key, u32 idx), ascending.
#define TILE_B 2048

__global__ __launch_bounds__(1024) void knn_finalize_kernel(
        const float4* __restrict__ pre4, const float4* __restrict__ cur4,
        const float* __restrict__ ups,
        const unsigned* __restrict__ c2p,
        float* __restrict__ out) {
    __shared__ float4 sc[TILE_B];
    const int tid  = threadIdx.x;
    const int lane = tid & 63;
    const int w    = tid >> 6;
    const int i0   = blockIdx.x * 16 + w;

    const float4 p0 = pre4[i0];   // (-2p, |p|^2)

    unsigned ld0 = MAPPED_INF, li0 = 0u;
    float t80 = __int_as_float(0x7F800000);

    for (int tile = 0; tile < N_CUR; tile += TILE_B) {
        __syncthreads();
        for (int k = tid; k < TILE_B; k += 1024) sc[k] = cur4[tile + k];
        __syncthreads();

#pragma unroll 8
        for (int s = 0; s < TILE_B; s += 64) {
            float4 c = sc[s + lane];
            float d0 = fmaf(p0.x, c.x, fmaf(p0.y, c.y, fmaf(p0.z, c.z, c.w)));
            int jj = tile + s + lane;

            unsigned long long m0 = __ballot(d0 < t80);
            while (m0) {
                int src = __ffsll(m0) - 1;
                float fd = __uint_as_float(shfl_u32(__float_as_uint(d0), src));
                unsigned kd = key_of(fd);
                unsigned kj = shfl_u32((unsigned)jj, src);
                unsigned ud = shfl_up1_u32(ld0);
                unsigned uj = shfl_up1_u32(li0);
                if (lane == 0) ud = 0u;        // nothing shifts in below lane 0
                bool hi = kd < ud, lo = kd < ld0;
                ld0 = hi ? ud : (lo ? kd : ld0);
                li0 = hi ? uj : (lo ? kj : li0);
                t80 = float_of_key(shfl_u32(ld0, 7));
                m0 = (m0 & (m0 - 1)) & __ballot(d0 < t80);
            }
        }
    }

    // finalize: lanes 0..7 hold this pre's ascending top-8.
    // True distance recomputed in direct form; p recovered exactly (* -0.5).
    unsigned j = shfl_u32(li0, lane & 7);

    float contrib = 0.f;
    if (lane < 8) {
        float4 c = cur4[j];
        float px = -0.5f * p0.x;
        float py = -0.5f * p0.y;
        float pz = -0.5f * p0.z;
        float dx = c.x - px, dy = c.y - py, dz = c.z - pz;
        float dsq = fmaf(dx, dx, fmaf(dy, dy, dz * dz));
        unsigned owner = c2p[j];
        contrib = (owner == (unsigned)i0) ? sqrtf(dsq) : 0.f;
    }
    contrib += __shfl_xor(contrib, 1);
    contrib += __shfl_xor(contrib, 2);
    contrib += __shfl_xor(contrib, 4);
    if (lane == 0) out[i0] = contrib / ups[i0];
}

// ---------- launch ----------
extern "C" void kernel_launch(void* const* d_in, const int* in_sizes, int n_in,
                              void* d_out, int out_size, void* d_ws, size_t ws_size,
                              hipStream_t stream) {
    const float* pre = (const float*)d_in[0];   // (1,3,8192)
    const float* cur = (const float*)d_in[1];   // (1,3,16384)
    const float* ups = (const float*)d_in[2];   // (1,8192)
    float* out = (float*)d_out;                 // (1,8192)

    char* ws = (char*)d_ws;
    unsigned* c2p = (unsigned*)ws;                    //  64 KB
    float4*   pre4 = (float4*)(ws + 65536);           // 128 KB
    float4*   cur4 = (float4*)(ws + 65536 + 131072);  // 256 KB

    prep_kernel<<<N_CUR / 256, 256, 0, stream>>>(pre, cur, pre4, cur4);

    // 512 blocks x 16 waves = 8192 waves = 100% of chip wave capacity
    cur2pre_kernel<<<N_CUR / 32, 1024, 0, stream>>>(pre4, cur4, c2p);

    knn_finalize_kernel<<<N_PRE / 16, 1024, 0, stream>>>(pre4, cur4, ups, c2p, out);
}